// Round 1
// baseline (6499.733 us; speedup 1.0000x reference)
//
#include <hip/hip_runtime.h>
#include <math.h>

#define N_NODES 20000
#define E_EDGES 80000
#define BATCH 32
#define FPD 1024
#define ODIM 128
#define LLEN 384
#define DDIM 80
#define TDIM 63
#define DMODEL 64
#define NHEAD 4
#define HDIM 16
#define FFDIM 128
#define NLAYER 2
#define SEQLEN 768

__device__ __forceinline__ float leakyf(float v) { return v >= 0.f ? v : 0.01f * v; }

// ---------------- GEMM: Out[m][n] = sum_k X[m*K+k] * W[n*K+k] -------------
// 64x64 tile, BK=16, 256 threads, 4x4 per thread, fp32.
__global__ __launch_bounds__(256) void gemm_xwt(const float* __restrict__ X,
                                                const float* __restrict__ W,
                                                float* __restrict__ Out,
                                                int M, int Nn, int K) {
    __shared__ float As[16][68];
    __shared__ float Bs[16][68];
    int tid = threadIdx.x;
    int tx = tid & 15, ty = tid >> 4;
    int row0 = blockIdx.y * 64, col0 = blockIdx.x * 64;
    int lk = tid & 15, lm = tid >> 4;
    float c[4][4] = {};
    for (int k0 = 0; k0 < K; k0 += 16) {
#pragma unroll
        for (int p = 0; p < 4; ++p) {
            int m = lm + p * 16;
            int gr = row0 + m;
            int gc = col0 + m;
            As[lk][m] = (gr < M) ? X[(size_t)gr * K + k0 + lk] : 0.f;
            Bs[lk][m] = (gc < Nn) ? W[(size_t)gc * K + k0 + lk] : 0.f;
        }
        __syncthreads();
#pragma unroll
        for (int kk = 0; kk < 16; ++kk) {
            float a[4], b[4];
            *(float4*)a = *(const float4*)&As[kk][ty * 4];
            *(float4*)b = *(const float4*)&Bs[kk][tx * 4];
#pragma unroll
            for (int i = 0; i < 4; ++i)
#pragma unroll
                for (int j = 0; j < 4; ++j) c[i][j] = fmaf(a[i], b[j], c[i][j]);
        }
        __syncthreads();
    }
#pragma unroll
    for (int i = 0; i < 4; ++i) {
        int gr = row0 + ty * 4 + i;
        if (gr < M) {
            float4 v = make_float4(c[i][0], c[i][1], c[i][2], c[i][3]);
            *(float4*)&Out[(size_t)gr * Nn + col0 + tx * 4] = v;
        }
    }
}

// ---------------- GCN helpers -------------------------------------------
__global__ __launch_bounds__(256) void deg_kernel(const int* __restrict__ ei, float* __restrict__ deg) {
    int e = blockIdx.x * 256 + threadIdx.x;
    if (e < E_EDGES) atomicAdd(&deg[ei[E_EDGES + e]], 1.0f);
}

__global__ __launch_bounds__(256) void dinv_kernel(float* __restrict__ deg) {
    int i = blockIdx.x * 256 + threadIdx.x;
    if (i < N_NODES) deg[i] = rsqrtf(deg[i] + 1.0f);  // +1 self loop; always > 0
}

__global__ __launch_bounds__(256) void scatter_kernel(const float* __restrict__ h,
                                                      const int* __restrict__ ei,
                                                      const float* __restrict__ dinv,
                                                      float* __restrict__ acc) {
    int e = blockIdx.x;
    int src = ei[e];
    int dst = ei[E_EDGES + e];
    float nrm = dinv[src] * dinv[dst];
    const float4* hs = (const float4*)(h + (size_t)src * FPD);
    float* ad = acc + (size_t)dst * FPD;
    int f = threadIdx.x;
    float4 v = hs[f];
    atomicAdd(ad + f * 4 + 0, v.x * nrm);
    atomicAdd(ad + f * 4 + 1, v.y * nrm);
    atomicAdd(ad + f * 4 + 2, v.z * nrm);
    atomicAdd(ad + f * 4 + 3, v.w * nrm);
}

__global__ __launch_bounds__(256) void gcn_fin(const float* __restrict__ h,
                                               const float* __restrict__ dinv,
                                               const float* __restrict__ bias,
                                               float* __restrict__ acc) {
    size_t i4 = (size_t)blockIdx.x * 256 + threadIdx.x;
    if (i4 >= (size_t)N_NODES * FPD / 4) return;
    int node = (int)(i4 / (FPD / 4));
    int f = (int)(i4 % (FPD / 4)) * 4;
    float d = dinv[node];
    float d2 = d * d;
    float4 a = *(float4*)&acc[i4 * 4];
    float4 hv = *(const float4*)&h[i4 * 4];
    a.x = leakyf(a.x + hv.x * d2 + bias[f + 0]);
    a.y = leakyf(a.y + hv.y * d2 + bias[f + 1]);
    a.z = leakyf(a.z + hv.z * d2 + bias[f + 2]);
    a.w = leakyf(a.w + hv.w * d2 + bias[f + 3]);
    *(float4*)&acc[i4 * 4] = a;
}

__global__ __launch_bounds__(256) void bstart_kernel(const int* __restrict__ batch, int* __restrict__ bstart) {
    int i = blockIdx.x * 256 + threadIdx.x;
    if (i >= N_NODES) return;
    int b = batch[i];
    if (i == 0) {
        for (int x = 0; x <= b; ++x) bstart[x] = 0;
    } else {
        int pb = batch[i - 1];
        for (int x = pb + 1; x <= b; ++x) bstart[x] = i;
    }
    if (i == N_NODES - 1) {
        for (int x = b + 1; x <= BATCH; ++x) bstart[x] = N_NODES;
    }
}

__global__ __launch_bounds__(256) void pool_kernel(const float* __restrict__ x,
                                                   const int* __restrict__ bstart,
                                                   float* __restrict__ pooled) {
    int b = blockIdx.x;
    int f = blockIdx.y * 256 + threadIdx.x;
    int s = bstart[b], e = bstart[b + 1];
    float acc = 0.f;
    for (int i = s; i < e; ++i) acc += x[(size_t)i * FPD + f];
    float cnt = (float)(e - s);
    pooled[b * FPD + f] = acc / fmaxf(cnt, 1.0f);
}

__global__ __launch_bounds__(64) void fc_kernel(const float* __restrict__ pooled,
                                                const float* __restrict__ w,
                                                const float* __restrict__ bias,
                                                float* __restrict__ out) {
    __shared__ float xs[FPD];
    int b = blockIdx.x;
    int j = blockIdx.y * 64 + threadIdx.x;
    for (int k = threadIdx.x; k < FPD; k += 64) xs[k] = pooled[b * FPD + k];
    __syncthreads();
    float acc = bias[j];
    const float* wr = w + (size_t)j * FPD;
    for (int k = 0; k < FPD; k += 4) {
        float4 wv = *(const float4*)&wr[k];
        acc += xs[k] * wv.x + xs[k + 1] * wv.y + xs[k + 2] * wv.z + xs[k + 3] * wv.w;
    }
    out[b * ODIM + j] = leakyf(acc);
}

// ---------------- sequence build ----------------------------------------
__global__ __launch_bounds__(64) void red_kernel(const float* __restrict__ m,
                                                 const float* __restrict__ rw,
                                                 const float* __restrict__ rb,
                                                 float* __restrict__ outp) {
    int rp = blockIdx.x;  // b*LLEN + pos
    __shared__ float xs[DDIM];
    int t = threadIdx.x;
    for (int k = t; k < DDIM; k += 64) xs[k] = m[(size_t)rp * DDIM + k];
    __syncthreads();
    if (t < TDIM) {
        float acc = rb[t];
        const float* wr = rw + (size_t)t * DDIM;
        for (int k = 0; k < DDIM; ++k) acc += xs[k] * wr[k];
        outp[(size_t)rp * TDIM + t] = acc;
    }
}

__global__ __launch_bounds__(64) void seq_kernel(const float* __restrict__ ps,
                                                 const float* __restrict__ pf,
                                                 const int* __restrict__ slen,
                                                 const int* __restrict__ flen,
                                                 float* __restrict__ seq) {
    int bp = blockIdx.x;
    int b = bp / SEQLEN;
    int pos = bp % SEQLEN;
    int d = threadIdx.x;
    int sl = slen[b], fl = flen[b];
    float v = 0.f;
    if (d == 63) {
        v = (pos < sl) ? 1.f : 0.f;
    } else {
        if (pos < sl) v = ps[((size_t)b * LLEN + pos) * TDIM + d];
        else if (pos < sl + fl) v = pf[((size_t)b * LLEN + (pos - sl)) * TDIM + d];
    }
    seq[(size_t)bp * DMODEL + d] = v;
}

// ---------------- transformer -------------------------------------------
__global__ __launch_bounds__(192) void qkv_kernel(const float* __restrict__ x,
                                                  const float* __restrict__ w,
                                                  const float* __restrict__ bias,
                                                  float* __restrict__ out) {
    __shared__ float wsh[192 * 65];
    __shared__ float bsh[192];
    __shared__ float xsh[64];
    int t = threadIdx.x;
    for (int idx = t; idx < 192 * 64; idx += 192) wsh[(idx >> 6) * 65 + (idx & 63)] = w[idx];
    bsh[t] = bias[t];
    int row0 = blockIdx.x * 16;
    for (int r = 0; r < 16; ++r) {
        int row = row0 + r;
        __syncthreads();
        if (t < 64) xsh[t] = x[(size_t)row * DMODEL + t];
        __syncthreads();
        float acc = bsh[t];
        const float* wr = &wsh[t * 65];
#pragma unroll
        for (int k = 0; k < 64; ++k) acc += xsh[k] * wr[k];
        out[(size_t)row * 192 + t] = acc;
    }
}

#define KCH 256
__global__ __launch_bounds__(256) void attn_kernel(const float* __restrict__ qkv,
                                                   const int* __restrict__ slen,
                                                   const int* __restrict__ flen,
                                                   float* __restrict__ attno) {
    __shared__ float Ks[KCH * 16];
    __shared__ float Vs[KCH * 16];
    int bh = blockIdx.x;
    int b = bh >> 2;
    int h = bh & 3;
    int len = min(slen[b] + flen[b], SEQLEN);
    int t = threadIdx.x;
    float q[3][16], o[3][16], mx[3], sm[3];
#pragma unroll
    for (int r = 0; r < 3; ++r) {
        int row = t + r * 256;
        const float* qp = qkv + ((size_t)b * SEQLEN + row) * 192 + h * 16;
#pragma unroll
        for (int d = 0; d < 16; ++d) { q[r][d] = qp[d]; o[r][d] = 0.f; }
        mx[r] = -1e30f;
        sm[r] = 0.f;
    }
    for (int c0 = 0; c0 < len; c0 += KCH) {
        int cl = min(KCH, len - c0);
        __syncthreads();
        for (int idx = t; idx < cl * 16; idx += 256) {
            int kr = idx >> 4, d = idx & 15;
            const float* kp = qkv + ((size_t)b * SEQLEN + c0 + kr) * 192 + 64 + h * 16;
            Ks[idx] = kp[d];
            Vs[idx] = kp[64 + d];
        }
        __syncthreads();
        for (int kk = 0; kk < cl; ++kk) {
            float kv[16], vv[16];
            *(float4*)&kv[0] = *(const float4*)&Ks[kk * 16 + 0];
            *(float4*)&kv[4] = *(const float4*)&Ks[kk * 16 + 4];
            *(float4*)&kv[8] = *(const float4*)&Ks[kk * 16 + 8];
            *(float4*)&kv[12] = *(const float4*)&Ks[kk * 16 + 12];
            *(float4*)&vv[0] = *(const float4*)&Vs[kk * 16 + 0];
            *(float4*)&vv[4] = *(const float4*)&Vs[kk * 16 + 4];
            *(float4*)&vv[8] = *(const float4*)&Vs[kk * 16 + 8];
            *(float4*)&vv[12] = *(const float4*)&Vs[kk * 16 + 12];
#pragma unroll
            for (int r = 0; r < 3; ++r) {
                float sc = 0.f;
#pragma unroll
                for (int d = 0; d < 16; ++d) sc = fmaf(q[r][d], kv[d], sc);
                sc *= 0.25f;
                float p;
                if (sc > mx[r]) {
                    float corr = __expf(mx[r] - sc);
                    sm[r] *= corr;
#pragma unroll
                    for (int d = 0; d < 16; ++d) o[r][d] *= corr;
                    mx[r] = sc;
                    p = 1.f;
                } else {
                    p = __expf(sc - mx[r]);
                }
                sm[r] += p;
#pragma unroll
                for (int d = 0; d < 16; ++d) o[r][d] = fmaf(p, vv[d], o[r][d]);
            }
        }
    }
#pragma unroll
    for (int r = 0; r < 3; ++r) {
        int row = t + r * 256;
        float inv = 1.f / sm[r];
        float* op = attno + ((size_t)b * SEQLEN + row) * DMODEL + h * 16;
#pragma unroll
        for (int d = 0; d < 16; ++d) op[d] = o[r][d] * inv;
    }
}

__global__ __launch_bounds__(64) void projln_kernel(const float* __restrict__ attno,
                                                    const float* __restrict__ ow,
                                                    const float* __restrict__ ob,
                                                    const float* __restrict__ lnw,
                                                    const float* __restrict__ lnb,
                                                    float* __restrict__ x) {
    int row = blockIdx.x;
    int j = threadIdx.x;
    __shared__ float os[64];
    os[j] = attno[(size_t)row * DMODEL + j];
    __syncthreads();
    float acc = ob[j];
    const float* wr = ow + j * 64;
#pragma unroll
    for (int k = 0; k < 64; ++k) acc += os[k] * wr[k];
    float r = x[(size_t)row * DMODEL + j] + acc;
    float sum = r;
#pragma unroll
    for (int off = 32; off; off >>= 1) sum += __shfl_xor(sum, off);
    float mean = sum * (1.f / 64.f);
    float dv = r - mean;
    float vs = dv * dv;
#pragma unroll
    for (int off = 32; off; off >>= 1) vs += __shfl_xor(vs, off);
    float var = vs * (1.f / 64.f);
    x[(size_t)row * DMODEL + j] = dv * rsqrtf(var + 1e-5f) * lnw[j] + lnb[j];
}

__global__ __launch_bounds__(128) void ffnln_kernel(const float* __restrict__ f1w,
                                                    const float* __restrict__ f1b,
                                                    const float* __restrict__ f2w,
                                                    const float* __restrict__ f2b,
                                                    const float* __restrict__ lnw,
                                                    const float* __restrict__ lnb,
                                                    float* __restrict__ x) {
    int row = blockIdx.x;
    int t = threadIdx.x;
    __shared__ float xs[64];
    __shared__ float hs[128];
    if (t < 64) xs[t] = x[(size_t)row * DMODEL + t];
    __syncthreads();
    float acc = f1b[t];
    const float* wr = f1w + t * 64;
#pragma unroll
    for (int k = 0; k < 64; ++k) acc += xs[k] * wr[k];
    hs[t] = fmaxf(acc, 0.f);
    __syncthreads();
    if (t < 64) {
        float a2 = f2b[t];
        const float* w2 = f2w + t * 128;
#pragma unroll
        for (int k = 0; k < 128; ++k) a2 += hs[k] * w2[k];
        float r = xs[t] + a2;
        float sum = r;
#pragma unroll
        for (int off = 32; off; off >>= 1) sum += __shfl_xor(sum, off);
        float mean = sum * (1.f / 64.f);
        float dv = r - mean;
        float vs = dv * dv;
#pragma unroll
        for (int off = 32; off; off >>= 1) vs += __shfl_xor(vs, off);
        float var = vs * (1.f / 64.f);
        x[(size_t)row * DMODEL + t] = dv * rsqrtf(var + 1e-5f) * lnw[t] + lnb[t];
    }
}

__global__ __launch_bounds__(64) void tpool_kernel(const float* __restrict__ x,
                                                   const int* __restrict__ slen,
                                                   const int* __restrict__ flen,
                                                   float* __restrict__ o) {
    int b = blockIdx.x;
    int d = threadIdx.x;
    int len = min(slen[b] + flen[b], SEQLEN);
    float acc = 0.f;
    for (int r = 0; r < len; ++r) acc += x[((size_t)b * SEQLEN + r) * DMODEL + d];
    o[b * DMODEL + d] = acc / (float)len;
}

__global__ __launch_bounds__(128) void final_kernel(const float* __restrict__ f1,
                                                    const float* __restrict__ f2,
                                                    const float* __restrict__ o1,
                                                    const float* __restrict__ o2,
                                                    const float* __restrict__ fw,
                                                    const float* __restrict__ fb,
                                                    float* __restrict__ out) {
    int b = blockIdx.x;
    int t = threadIdx.x;
    float acc = 0.f;
    for (int k = t; k < 384; k += 128) {
        float v;
        if (k < 128) v = f1[b * ODIM + k];
        else if (k < 256) v = f2[b * ODIM + (k - 128)];
        else if (k < 320) v = o1[b * DMODEL + (k - 256)];
        else v = o2[b * DMODEL + (k - 320)];
        acc += v * fw[k];
    }
    __shared__ float red[2];
#pragma unroll
    for (int off = 32; off; off >>= 1) acc += __shfl_xor(acc, off);
    if ((t & 63) == 0) red[t >> 6] = acc;
    __syncthreads();
    if (t == 0) out[b] = red[0] + red[1] + fb[0];
}

// ---------------- host orchestration ------------------------------------
static void run_gcn_branch(const float* x, const int* ei, const int* batch,
                           const float* gw, const float* gb,
                           const float* fw, const float* fb,
                           float* h, float* acc, float* dinv, int* bstart,
                           float* pooled, float* feat, hipStream_t stream) {
    dim3 g1(FPD / 64, (N_NODES + 63) / 64);
    gemm_xwt<<<g1, 256, 0, stream>>>(x, gw, h, N_NODES, FPD, FPD);
    hipMemsetAsync(dinv, 0, N_NODES * sizeof(float), stream);
    deg_kernel<<<(E_EDGES + 255) / 256, 256, 0, stream>>>(ei, dinv);
    dinv_kernel<<<(N_NODES + 255) / 256, 256, 0, stream>>>(dinv);
    hipMemsetAsync(acc, 0, (size_t)N_NODES * FPD * sizeof(float), stream);
    scatter_kernel<<<E_EDGES, 256, 0, stream>>>(h, ei, dinv, acc);
    gcn_fin<<<(N_NODES * (FPD / 4) + 255) / 256, 256, 0, stream>>>(h, dinv, gb, acc);
    bstart_kernel<<<(N_NODES + 255) / 256, 256, 0, stream>>>(batch, bstart);
    pool_kernel<<<dim3(BATCH, FPD / 256), 256, 0, stream>>>(acc, bstart, pooled);
    fc_kernel<<<dim3(BATCH, ODIM / 64), 64, 0, stream>>>(pooled, fw, fb, feat);
}

static void run_sequence(const float* straight, const float* flipped,
                         const int* sl, const int* fl,
                         const float* red_w, const float* red_b,
                         const float* qkv_w, const float* qkv_b,
                         const float* out_w, const float* out_b,
                         const float* ln1_w, const float* ln1_b,
                         const float* ff1_w, const float* ff1_b,
                         const float* ff2_w, const float* ff2_b,
                         const float* ln2_w, const float* ln2_b,
                         float* ps, float* pf, float* xb, float* qkvb, float* attno,
                         float* obuf, hipStream_t stream) {
    red_kernel<<<BATCH * LLEN, 64, 0, stream>>>(straight, red_w, red_b, ps);
    red_kernel<<<BATCH * LLEN, 64, 0, stream>>>(flipped, red_w, red_b, pf);
    seq_kernel<<<BATCH * SEQLEN, 64, 0, stream>>>(ps, pf, sl, fl, xb);
    for (int l = 0; l < NLAYER; ++l) {
        qkv_kernel<<<BATCH * SEQLEN / 16, 192, 0, stream>>>(
            xb, qkv_w + (size_t)l * 3 * DMODEL * DMODEL, qkv_b + l * 3 * DMODEL, qkvb);
        attn_kernel<<<BATCH * NHEAD, 256, 0, stream>>>(qkvb, sl, fl, attno);
        projln_kernel<<<BATCH * SEQLEN, 64, 0, stream>>>(
            attno, out_w + (size_t)l * DMODEL * DMODEL, out_b + l * DMODEL,
            ln1_w + l * DMODEL, ln1_b + l * DMODEL, xb);
        ffnln_kernel<<<BATCH * SEQLEN, 128, 0, stream>>>(
            ff1_w + (size_t)l * FFDIM * DMODEL, ff1_b + l * FFDIM,
            ff2_w + (size_t)l * DMODEL * FFDIM, ff2_b + l * DMODEL,
            ln2_w + l * DMODEL, ln2_b + l * DMODEL, xb);
    }
    tpool_kernel<<<BATCH, 64, 0, stream>>>(xb, sl, fl, obuf);
}

extern "C" void kernel_launch(void* const* d_in, const int* in_sizes, int n_in,
                              void* d_out, int out_size, void* d_ws, size_t ws_size,
                              hipStream_t stream) {
    const float* pro1_x = (const float*)d_in[0];
    const int* ei1 = (const int*)d_in[1];
    const int* batch1 = (const int*)d_in[2];
    const float* pro2_x = (const float*)d_in[3];
    const int* ei2 = (const int*)d_in[4];
    const int* batch2 = (const int*)d_in[5];
    const float* mas1_s = (const float*)d_in[6];
    const int* mas1_sl = (const int*)d_in[7];
    const float* mas1_f = (const float*)d_in[8];
    const int* mas1_fl = (const int*)d_in[9];
    const float* mas2_s = (const float*)d_in[10];
    const int* mas2_sl = (const int*)d_in[11];
    const float* mas2_f = (const float*)d_in[12];
    const int* mas2_fl = (const int*)d_in[13];
    const float* gcn1_w = (const float*)d_in[14];
    const float* gcn1_b = (const float*)d_in[15];
    const float* fc1_w = (const float*)d_in[16];
    const float* fc1_b = (const float*)d_in[17];
    const float* gcn2_w = (const float*)d_in[18];
    const float* gcn2_b = (const float*)d_in[19];
    const float* fc2_w = (const float*)d_in[20];
    const float* fc2_b = (const float*)d_in[21];
    const float* red_w = (const float*)d_in[22];
    const float* red_b = (const float*)d_in[23];
    const float* t_qkv_w = (const float*)d_in[24];
    const float* t_qkv_b = (const float*)d_in[25];
    const float* t_out_w = (const float*)d_in[26];
    const float* t_out_b = (const float*)d_in[27];
    const float* t_ln1_w = (const float*)d_in[28];
    const float* t_ln1_b = (const float*)d_in[29];
    const float* t_ff1_w = (const float*)d_in[30];
    const float* t_ff1_b = (const float*)d_in[31];
    const float* t_ff2_w = (const float*)d_in[32];
    const float* t_ff2_b = (const float*)d_in[33];
    const float* t_ln2_w = (const float*)d_in[34];
    const float* t_ln2_b = (const float*)d_in[35];
    const float* fin_w = (const float*)d_in[36];
    const float* fin_b = (const float*)d_in[37];
    float* out = (float*)d_out;

    float* ws = (float*)d_ws;
    float* h = ws;                                     // N*FP
    float* acc = h + (size_t)N_NODES * FPD;            // N*FP
    float* dinv = acc + (size_t)N_NODES * FPD;         // N
    int* bstart = (int*)(dinv + N_NODES);              // 33 ints (within 64-float gap)
    float* pooled = dinv + N_NODES + 64;               // B*FP
    float* feat1 = pooled + BATCH * FPD;               // B*OD
    float* feat2 = feat1 + BATCH * ODIM;               // B*OD
    float* ps = feat2 + BATCH * ODIM;                  // B*L*TD
    float* pf = ps + (size_t)BATCH * LLEN * TDIM;      // B*L*TD
    float* xb = pf + (size_t)BATCH * LLEN * TDIM;      // B*S*D
    float* qkvb = xb + (size_t)BATCH * SEQLEN * DMODEL;    // B*S*3D
    float* attno = qkvb + (size_t)BATCH * SEQLEN * 3 * DMODEL;  // B*S*D
    float* o1 = attno + (size_t)BATCH * SEQLEN * DMODEL;   // B*D
    float* o2 = o1 + BATCH * DMODEL;                   // B*D

    run_gcn_branch(pro1_x, ei1, batch1, gcn1_w, gcn1_b, fc1_w, fc1_b,
                   h, acc, dinv, bstart, pooled, feat1, stream);
    run_gcn_branch(pro2_x, ei2, batch2, gcn2_w, gcn2_b, fc2_w, fc2_b,
                   h, acc, dinv, bstart, pooled, feat2, stream);

    run_sequence(mas1_s, mas1_f, mas1_sl, mas1_fl, red_w, red_b,
                 t_qkv_w, t_qkv_b, t_out_w, t_out_b, t_ln1_w, t_ln1_b,
                 t_ff1_w, t_ff1_b, t_ff2_w, t_ff2_b, t_ln2_w, t_ln2_b,
                 ps, pf, xb, qkvb, attno, o1, stream);
    run_sequence(mas2_s, mas2_f, mas2_sl, mas2_fl, red_w, red_b,
                 t_qkv_w, t_qkv_b, t_out_w, t_out_b, t_ln1_w, t_ln1_b,
                 t_ff1_w, t_ff1_b, t_ff2_w, t_ff2_b, t_ln2_w, t_ln2_b,
                 ps, pf, xb, qkvb, attno, o2, stream);

    final_kernel<<<BATCH, 128, 0, stream>>>(feat1, feat2, o1, o2, fin_w, fin_b, out);
}

// Round 2
// 3627.308 us; speedup vs baseline: 1.7919x; 1.7919x over previous
//
#include <hip/hip_runtime.h>
#include <math.h>

#define N_NODES 20000
#define E_EDGES 80000
#define BATCH 32
#define FPD 1024
#define ODIM 128
#define LLEN 384
#define DDIM 80
#define TDIM 63
#define DMODEL 64
#define NHEAD 4
#define HDIM 16
#define FFDIM 128
#define NLAYER 2
#define SEQLEN 768

typedef __attribute__((ext_vector_type(8))) short short8;
typedef __attribute__((ext_vector_type(4))) float f32x4;

union Frag {
    short8 v;
    unsigned short u[8];
    unsigned long long d[2];
};

__device__ __forceinline__ float leakyf(float v) { return v >= 0.f ? v : 0.01f * v; }

__device__ __forceinline__ unsigned short f2bf_rne(float f) {
    unsigned int u = __float_as_uint(f);
    unsigned int r = u + 0x7FFFu + ((u >> 16) & 1u);
    return (unsigned short)(r >> 16);
}

// ---------------- split fp32 -> bf16 hi/lo --------------------------------
__global__ __launch_bounds__(256) void split_kernel(const float* __restrict__ in,
                                                    unsigned short* __restrict__ hi,
                                                    unsigned short* __restrict__ lo,
                                                    long n4) {
    long i = (long)blockIdx.x * 256 + threadIdx.x;
    if (i >= n4) return;
    float4 v = ((const float4*)in)[i];
    unsigned short h0 = f2bf_rne(v.x), h1 = f2bf_rne(v.y), h2 = f2bf_rne(v.z), h3 = f2bf_rne(v.w);
    float r0 = v.x - __uint_as_float((unsigned)h0 << 16);
    float r1 = v.y - __uint_as_float((unsigned)h1 << 16);
    float r2 = v.z - __uint_as_float((unsigned)h2 << 16);
    float r3 = v.w - __uint_as_float((unsigned)h3 << 16);
    unsigned long long hv = (unsigned long long)h0 | ((unsigned long long)h1 << 16) |
                            ((unsigned long long)h2 << 32) | ((unsigned long long)h3 << 48);
    unsigned long long lv = (unsigned long long)f2bf_rne(r0) | ((unsigned long long)f2bf_rne(r1) << 16) |
                            ((unsigned long long)f2bf_rne(r2) << 32) | ((unsigned long long)f2bf_rne(r3) << 48);
    ((unsigned long long*)hi)[i] = hv;
    ((unsigned long long*)lo)[i] = lv;
}

// ---------------- MFMA GEMM: Out[m][n] = sum_k X[m][k]*W[n][k] ------------
// split bf16: X ~ Xhi+Xlo, W ~ Whi+Wlo; acc += XhiWhi + XhiWlo + XloWhi.
// 128x128 tile, BK=32, 4 waves, per-wave 64x64 (4x4 frags of 16x16x32).
__global__ __launch_bounds__(256) void gemm_mfma(const unsigned short* __restrict__ Ahi,
                                                 const unsigned short* __restrict__ Alo,
                                                 const unsigned short* __restrict__ Bhi,
                                                 const unsigned short* __restrict__ Blo,
                                                 float* __restrict__ Out,
                                                 int M) {
    const int K = FPD, Nn = FPD;
    __shared__ unsigned short As[2][128][40];  // stride 40 bf16 = 80B: 16B-aligned rows, <=2-way bank conflict
    __shared__ unsigned short Bs[2][128][40];
    int tid = threadIdx.x;
    int row0 = blockIdx.x * 128, col0 = blockIdx.y * 128;
    int wave = tid >> 6, lane = tid & 63;
    int wr = wave >> 1, wc = wave & 1;
    int lr = lane & 15, lq = lane >> 4;
    f32x4 acc[4][4];
#pragma unroll
    for (int i = 0; i < 4; ++i)
#pragma unroll
        for (int j = 0; j < 4; ++j) acc[i][j] = (f32x4){0.f, 0.f, 0.f, 0.f};

    for (int k0 = 0; k0 < K; k0 += 32) {
        __syncthreads();
#pragma unroll
        for (int i = 0; i < 2; ++i) {
            int c = tid + 256 * i;       // 512 chunks of 8 bf16 cover 128x32
            int r = c >> 2, ko = (c & 3) * 8;
            int ar = row0 + r; if (ar >= M) ar = M - 1;
            size_t ga = (size_t)ar * K + k0 + ko;
            size_t gb = (size_t)(col0 + r) * K + k0 + ko;
            *(short8*)&As[0][r][ko] = *(const short8*)&Ahi[ga];
            *(short8*)&As[1][r][ko] = *(const short8*)&Alo[ga];
            *(short8*)&Bs[0][r][ko] = *(const short8*)&Bhi[gb];
            *(short8*)&Bs[1][r][ko] = *(const short8*)&Blo[gb];
        }
        __syncthreads();
        Frag ah[4], al[4], bh[4], bl[4];
#pragma unroll
        for (int f = 0; f < 4; ++f) {
            int arr = wr * 64 + f * 16 + lr;
            int brr = wc * 64 + f * 16 + lr;
            ah[f].d[0] = *(const unsigned long long*)&As[0][arr][4 * lq];
            ah[f].d[1] = *(const unsigned long long*)&As[0][arr][16 + 4 * lq];
            al[f].d[0] = *(const unsigned long long*)&As[1][arr][4 * lq];
            al[f].d[1] = *(const unsigned long long*)&As[1][arr][16 + 4 * lq];
            bh[f].d[0] = *(const unsigned long long*)&Bs[0][brr][4 * lq];
            bh[f].d[1] = *(const unsigned long long*)&Bs[0][brr][16 + 4 * lq];
            bl[f].d[0] = *(const unsigned long long*)&Bs[1][brr][4 * lq];
            bl[f].d[1] = *(const unsigned long long*)&Bs[1][brr][16 + 4 * lq];
        }
#pragma unroll
        for (int mf = 0; mf < 4; ++mf)
#pragma unroll
            for (int nf = 0; nf < 4; ++nf) {
                acc[mf][nf] = __builtin_amdgcn_mfma_f32_16x16x32_bf16(ah[mf].v, bh[nf].v, acc[mf][nf], 0, 0, 0);
                acc[mf][nf] = __builtin_amdgcn_mfma_f32_16x16x32_bf16(ah[mf].v, bl[nf].v, acc[mf][nf], 0, 0, 0);
                acc[mf][nf] = __builtin_amdgcn_mfma_f32_16x16x32_bf16(al[mf].v, bh[nf].v, acc[mf][nf], 0, 0, 0);
            }
    }
    // C/D layout (HW-verified): col = lane&15, row = 4*(lane>>4)+reg
#pragma unroll
    for (int mf = 0; mf < 4; ++mf)
#pragma unroll
        for (int r = 0; r < 4; ++r) {
            int m = row0 + wr * 64 + mf * 16 + 4 * lq + r;
            if (m < M) {
#pragma unroll
                for (int nf = 0; nf < 4; ++nf)
                    Out[(size_t)m * Nn + col0 + wc * 64 + nf * 16 + lr] = acc[mf][nf][r];
            }
        }
}

// ---------------- GCN aggregation via CSR gather --------------------------
__global__ __launch_bounds__(256) void count_kernel(const int* __restrict__ ei, int* __restrict__ cnt) {
    int e = blockIdx.x * 256 + threadIdx.x;
    if (e < E_EDGES) atomicAdd(&cnt[ei[E_EDGES + e]], 1);
}

__global__ __launch_bounds__(256) void dinv_from_cnt(const int* __restrict__ cnt, float* __restrict__ dinv) {
    int i = blockIdx.x * 256 + threadIdx.x;
    if (i < N_NODES) dinv[i] = rsqrtf((float)cnt[i] + 1.0f);  // +1 self loop
}

__global__ __launch_bounds__(1024) void scan_kernel(const int* __restrict__ cnt,
                                                    int* __restrict__ rowptr,
                                                    int* __restrict__ cursor) {
    __shared__ int sh[1024];
    int t = threadIdx.x;
    int run = 0;
    for (int c0 = 0; c0 < N_NODES; c0 += 1024) {
        int i = c0 + t;
        int v = (i < N_NODES) ? cnt[i] : 0;
        sh[t] = v;
        __syncthreads();
        for (int off = 1; off < 1024; off <<= 1) {
            int add = (t >= off) ? sh[t - off] : 0;
            __syncthreads();
            sh[t] += add;
            __syncthreads();
        }
        if (i < N_NODES) {
            int ex = run + sh[t] - v;
            rowptr[i] = ex;
            cursor[i] = ex;
        }
        int tot = sh[1023];
        __syncthreads();
        run += tot;
    }
    if (t == 0) rowptr[N_NODES] = run;
}

__global__ __launch_bounds__(256) void fill_kernel(const int* __restrict__ ei,
                                                   int* __restrict__ cursor,
                                                   int* __restrict__ adj) {
    int e = blockIdx.x * 256 + threadIdx.x;
    if (e >= E_EDGES) return;
    int dst = ei[E_EDGES + e];
    int pos = atomicAdd(&cursor[dst], 1);
    adj[pos] = ei[e];  // src
}

// one block per dst node: gather in-edges + self, add bias, leaky
__global__ __launch_bounds__(256) void gather_kernel(const float* __restrict__ h,
                                                     const int* __restrict__ rowptr,
                                                     const int* __restrict__ adj,
                                                     const float* __restrict__ dinv,
                                                     const float* __restrict__ bias,
                                                     float* __restrict__ out) {
    int nd = blockIdx.x;
    int t = threadIdx.x;
    int s = rowptr[nd], e = rowptr[nd + 1];
    float di = dinv[nd];
    const float4* h4 = (const float4*)h;
    float4 a = h4[(size_t)nd * 256 + t];
    float d2 = di * di;
    a.x *= d2; a.y *= d2; a.z *= d2; a.w *= d2;
    for (int j = s; j < e; ++j) {
        int src = adj[j];
        float nr = di * dinv[src];
        float4 v = h4[(size_t)src * 256 + t];
        a.x += v.x * nr; a.y += v.y * nr; a.z += v.z * nr; a.w += v.w * nr;
    }
    float4 b4 = *(const float4*)&bias[t * 4];
    a.x = leakyf(a.x + b4.x);
    a.y = leakyf(a.y + b4.y);
    a.z = leakyf(a.z + b4.z);
    a.w = leakyf(a.w + b4.w);
    ((float4*)out)[(size_t)nd * 256 + t] = a;
}

__global__ __launch_bounds__(256) void bstart_kernel(const int* __restrict__ batch, int* __restrict__ bstart) {
    int i = blockIdx.x * 256 + threadIdx.x;
    if (i >= N_NODES) return;
    int b = batch[i];
    if (i == 0) {
        for (int x = 0; x <= b; ++x) bstart[x] = 0;
    } else {
        int pb = batch[i - 1];
        for (int x = pb + 1; x <= b; ++x) bstart[x] = i;
    }
    if (i == N_NODES - 1) {
        for (int x = b + 1; x <= BATCH; ++x) bstart[x] = N_NODES;
    }
}

__global__ __launch_bounds__(256) void pool_kernel(const float* __restrict__ x,
                                                   const int* __restrict__ bstart,
                                                   float* __restrict__ pooled) {
    int b = blockIdx.x;
    int f = blockIdx.y * 256 + threadIdx.x;
    int s = bstart[b], e = bstart[b + 1];
    float acc = 0.f;
    for (int i = s; i < e; ++i) acc += x[(size_t)i * FPD + f];
    float cnt = (float)(e - s);
    pooled[b * FPD + f] = acc / fmaxf(cnt, 1.0f);
}

__global__ __launch_bounds__(64) void fc_kernel(const float* __restrict__ pooled,
                                                const float* __restrict__ w,
                                                const float* __restrict__ bias,
                                                float* __restrict__ out) {
    __shared__ float xs[FPD];
    int b = blockIdx.x;
    int j = blockIdx.y * 64 + threadIdx.x;
    for (int k = threadIdx.x; k < FPD; k += 64) xs[k] = pooled[b * FPD + k];
    __syncthreads();
    float acc = bias[j];
    const float* wr = w + (size_t)j * FPD;
    for (int k = 0; k < FPD; k += 4) {
        float4 wv = *(const float4*)&wr[k];
        acc += xs[k] * wv.x + xs[k + 1] * wv.y + xs[k + 2] * wv.z + xs[k + 3] * wv.w;
    }
    out[b * ODIM + j] = leakyf(acc);
}

// ---------------- sequence build ----------------------------------------
__global__ __launch_bounds__(64) void red_kernel(const float* __restrict__ m,
                                                 const float* __restrict__ rw,
                                                 const float* __restrict__ rb,
                                                 float* __restrict__ outp) {
    int rp = blockIdx.x;  // b*LLEN + pos
    __shared__ float xs[DDIM];
    int t = threadIdx.x;
    for (int k = t; k < DDIM; k += 64) xs[k] = m[(size_t)rp * DDIM + k];
    __syncthreads();
    if (t < TDIM) {
        float acc = rb[t];
        const float* wr = rw + (size_t)t * DDIM;
        for (int k = 0; k < DDIM; ++k) acc += xs[k] * wr[k];
        outp[(size_t)rp * TDIM + t] = acc;
    }
}

__global__ __launch_bounds__(64) void seq_kernel(const float* __restrict__ ps,
                                                 const float* __restrict__ pf,
                                                 const int* __restrict__ slen,
                                                 const int* __restrict__ flen,
                                                 float* __restrict__ seq) {
    int bp = blockIdx.x;
    int b = bp / SEQLEN;
    int pos = bp % SEQLEN;
    int d = threadIdx.x;
    int sl = slen[b], fl = flen[b];
    float v = 0.f;
    if (d == 63) {
        v = (pos < sl) ? 1.f : 0.f;
    } else {
        if (pos < sl) v = ps[((size_t)b * LLEN + pos) * TDIM + d];
        else if (pos < sl + fl) v = pf[((size_t)b * LLEN + (pos - sl)) * TDIM + d];
    }
    seq[(size_t)bp * DMODEL + d] = v;
}

// ---------------- transformer -------------------------------------------
__global__ __launch_bounds__(192) void qkv_kernel(const float* __restrict__ x,
                                                  const float* __restrict__ w,
                                                  const float* __restrict__ bias,
                                                  float* __restrict__ out) {
    __shared__ float wsh[192 * 65];
    __shared__ float bsh[192];
    __shared__ float xsh[64];
    int t = threadIdx.x;
    for (int idx = t; idx < 192 * 64; idx += 192) wsh[(idx >> 6) * 65 + (idx & 63)] = w[idx];
    bsh[t] = bias[t];
    int row0 = blockIdx.x * 16;
    for (int r = 0; r < 16; ++r) {
        int row = row0 + r;
        __syncthreads();
        if (t < 64) xsh[t] = x[(size_t)row * DMODEL + t];
        __syncthreads();
        float acc = bsh[t];
        const float* wr = &wsh[t * 65];
#pragma unroll
        for (int k = 0; k < 64; ++k) acc += xsh[k] * wr[k];
        out[(size_t)row * 192 + t] = acc;
    }
}

#define KCH 256
__global__ __launch_bounds__(256) void attn_kernel(const float* __restrict__ qkv,
                                                   const int* __restrict__ slen,
                                                   const int* __restrict__ flen,
                                                   float* __restrict__ attno) {
    __shared__ float Ks[KCH * 16];
    __shared__ float Vs[KCH * 16];
    int bh = blockIdx.x;
    int b = bh >> 2;
    int h = bh & 3;
    int len = min(slen[b] + flen[b], SEQLEN);
    int t = threadIdx.x;
    float q[3][16], o[3][16], mx[3], sm[3];
#pragma unroll
    for (int r = 0; r < 3; ++r) {
        int row = t + r * 256;
        const float* qp = qkv + ((size_t)b * SEQLEN + row) * 192 + h * 16;
#pragma unroll
        for (int d = 0; d < 16; ++d) { q[r][d] = qp[d]; o[r][d] = 0.f; }
        mx[r] = -1e30f;
        sm[r] = 0.f;
    }
    for (int c0 = 0; c0 < len; c0 += KCH) {
        int cl = min(KCH, len - c0);
        __syncthreads();
        for (int idx = t; idx < cl * 16; idx += 256) {
            int kr = idx >> 4, d = idx & 15;
            const float* kp = qkv + ((size_t)b * SEQLEN + c0 + kr) * 192 + 64 + h * 16;
            Ks[idx] = kp[d];
            Vs[idx] = kp[64 + d];
        }
        __syncthreads();
        for (int kk = 0; kk < cl; ++kk) {
            float kv[16], vv[16];
            *(float4*)&kv[0] = *(const float4*)&Ks[kk * 16 + 0];
            *(float4*)&kv[4] = *(const float4*)&Ks[kk * 16 + 4];
            *(float4*)&kv[8] = *(const float4*)&Ks[kk * 16 + 8];
            *(float4*)&kv[12] = *(const float4*)&Ks[kk * 16 + 12];
            *(float4*)&vv[0] = *(const float4*)&Vs[kk * 16 + 0];
            *(float4*)&vv[4] = *(const float4*)&Vs[kk * 16 + 4];
            *(float4*)&vv[8] = *(const float4*)&Vs[kk * 16 + 8];
            *(float4*)&vv[12] = *(const float4*)&Vs[kk * 16 + 12];
#pragma unroll
            for (int r = 0; r < 3; ++r) {
                float sc = 0.f;
#pragma unroll
                for (int d = 0; d < 16; ++d) sc = fmaf(q[r][d], kv[d], sc);
                sc *= 0.25f;
                float p;
                if (sc > mx[r]) {
                    float corr = __expf(mx[r] - sc);
                    sm[r] *= corr;
#pragma unroll
                    for (int d = 0; d < 16; ++d) o[r][d] *= corr;
                    mx[r] = sc;
                    p = 1.f;
                } else {
                    p = __expf(sc - mx[r]);
                }
                sm[r] += p;
#pragma unroll
                for (int d = 0; d < 16; ++d) o[r][d] = fmaf(p, vv[d], o[r][d]);
            }
        }
    }
#pragma unroll
    for (int r = 0; r < 3; ++r) {
        int row = t + r * 256;
        float inv = 1.f / sm[r];
        float* op = attno + ((size_t)b * SEQLEN + row) * DMODEL + h * 16;
#pragma unroll
        for (int d = 0; d < 16; ++d) op[d] = o[r][d] * inv;
    }
}

__global__ __launch_bounds__(64) void projln_kernel(const float* __restrict__ attno,
                                                    const float* __restrict__ ow,
                                                    const float* __restrict__ ob,
                                                    const float* __restrict__ lnw,
                                                    const float* __restrict__ lnb,
                                                    float* __restrict__ x) {
    int row = blockIdx.x;
    int j = threadIdx.x;
    __shared__ float os[64];
    os[j] = attno[(size_t)row * DMODEL + j];
    __syncthreads();
    float acc = ob[j];
    const float* wr = ow + j * 64;
#pragma unroll
    for (int k = 0; k < 64; ++k) acc += os[k] * wr[k];
    float r = x[(size_t)row * DMODEL + j] + acc;
    float sum = r;
#pragma unroll
    for (int off = 32; off; off >>= 1) sum += __shfl_xor(sum, off);
    float mean = sum * (1.f / 64.f);
    float dv = r - mean;
    float vs = dv * dv;
#pragma unroll
    for (int off = 32; off; off >>= 1) vs += __shfl_xor(vs, off);
    float var = vs * (1.f / 64.f);
    x[(size_t)row * DMODEL + j] = dv * rsqrtf(var + 1e-5f) * lnw[j] + lnb[j];
}

__global__ __launch_bounds__(128) void ffnln_kernel(const float* __restrict__ f1w,
                                                    const float* __restrict__ f1b,
                                                    const float* __restrict__ f2w,
                                                    const float* __restrict__ f2b,
                                                    const float* __restrict__ lnw,
                                                    const float* __restrict__ lnb,
                                                    float* __restrict__ x) {
    int row = blockIdx.x;
    int t = threadIdx.x;
    __shared__ float xs[64];
    __shared__ float hs[128];
    if (t < 64) xs[t] = x[(size_t)row * DMODEL + t];
    __syncthreads();
    float acc = f1b[t];
    const float* wr = f1w + t * 64;
#pragma unroll
    for (int k = 0; k < 64; ++k) acc += xs[k] * wr[k];
    hs[t] = fmaxf(acc, 0.f);
    __syncthreads();
    if (t < 64) {
        float a2 = f2b[t];
        const float* w2 = f2w + t * 128;
#pragma unroll
        for (int k = 0; k < 128; ++k) a2 += hs[k] * w2[k];
        float r = xs[t] + a2;
        float sum = r;
#pragma unroll
        for (int off = 32; off; off >>= 1) sum += __shfl_xor(sum, off);
        float mean = sum * (1.f / 64.f);
        float dv = r - mean;
        float vs = dv * dv;
#pragma unroll
        for (int off = 32; off; off >>= 1) vs += __shfl_xor(vs, off);
        float var = vs * (1.f / 64.f);
        x[(size_t)row * DMODEL + t] = dv * rsqrtf(var + 1e-5f) * lnw[t] + lnb[t];
    }
}

__global__ __launch_bounds__(64) void tpool_kernel(const float* __restrict__ x,
                                                   const int* __restrict__ slen,
                                                   const int* __restrict__ flen,
                                                   float* __restrict__ o) {
    int b = blockIdx.x;
    int d = threadIdx.x;
    int len = min(slen[b] + flen[b], SEQLEN);
    float acc = 0.f;
    for (int r = 0; r < len; ++r) acc += x[((size_t)b * SEQLEN + r) * DMODEL + d];
    o[b * DMODEL + d] = acc / (float)len;
}

__global__ __launch_bounds__(128) void final_kernel(const float* __restrict__ f1,
                                                    const float* __restrict__ f2,
                                                    const float* __restrict__ o1,
                                                    const float* __restrict__ o2,
                                                    const float* __restrict__ fw,
                                                    const float* __restrict__ fb,
                                                    float* __restrict__ out) {
    int b = blockIdx.x;
    int t = threadIdx.x;
    float acc = 0.f;
    for (int k = t; k < 384; k += 128) {
        float v;
        if (k < 128) v = f1[b * ODIM + k];
        else if (k < 256) v = f2[b * ODIM + (k - 128)];
        else if (k < 320) v = o1[b * DMODEL + (k - 256)];
        else v = o2[b * DMODEL + (k - 320)];
        acc += v * fw[k];
    }
    __shared__ float red[2];
#pragma unroll
    for (int off = 32; off; off >>= 1) acc += __shfl_xor(acc, off);
    if ((t & 63) == 0) red[t >> 6] = acc;
    __syncthreads();
    if (t == 0) out[b] = red[0] + red[1] + fb[0];
}

// ---------------- host orchestration ------------------------------------
static void run_gcn_branch(const float* x, const int* ei, const int* batch,
                           const float* gw, const float* gb,
                           const float* fw, const float* fb,
                           float* h, unsigned short* xhi, unsigned short* xlo,
                           unsigned short* whi, unsigned short* wlo,
                           float* acc, float* dinv, int* cnt, int* rowptr, int* cursor,
                           int* adj, int* bstart, float* pooled, float* feat,
                           hipStream_t stream) {
    split_kernel<<<(N_NODES * (FPD / 4) + 255) / 256, 256, 0, stream>>>(x, xhi, xlo, (long)N_NODES * FPD / 4);
    split_kernel<<<(FPD * (FPD / 4) + 255) / 256, 256, 0, stream>>>(gw, whi, wlo, (long)FPD * FPD / 4);
    gemm_mfma<<<dim3((N_NODES + 127) / 128, FPD / 128), 256, 0, stream>>>(xhi, xlo, whi, wlo, h, N_NODES);
    hipMemsetAsync(cnt, 0, N_NODES * sizeof(int), stream);
    count_kernel<<<(E_EDGES + 255) / 256, 256, 0, stream>>>(ei, cnt);
    dinv_from_cnt<<<(N_NODES + 255) / 256, 256, 0, stream>>>(cnt, dinv);
    scan_kernel<<<1, 1024, 0, stream>>>(cnt, rowptr, cursor);
    fill_kernel<<<(E_EDGES + 255) / 256, 256, 0, stream>>>(ei, cursor, adj);
    gather_kernel<<<N_NODES, 256, 0, stream>>>(h, rowptr, adj, dinv, gb, acc);
    bstart_kernel<<<(N_NODES + 255) / 256, 256, 0, stream>>>(batch, bstart);
    pool_kernel<<<dim3(BATCH, FPD / 256), 256, 0, stream>>>(acc, bstart, pooled);
    fc_kernel<<<dim3(BATCH, ODIM / 64), 64, 0, stream>>>(pooled, fw, fb, feat);
}

static void run_sequence(const float* straight, const float* flipped,
                         const int* sl, const int* fl,
                         const float* red_w, const float* red_b,
                         const float* qkv_w, const float* qkv_b,
                         const float* out_w, const float* out_b,
                         const float* ln1_w, const float* ln1_b,
                         const float* ff1_w, const float* ff1_b,
                         const float* ff2_w, const float* ff2_b,
                         const float* ln2_w, const float* ln2_b,
                         float* ps, float* pf, float* xb, float* qkvb, float* attno,
                         float* obuf, hipStream_t stream) {
    red_kernel<<<BATCH * LLEN, 64, 0, stream>>>(straight, red_w, red_b, ps);
    red_kernel<<<BATCH * LLEN, 64, 0, stream>>>(flipped, red_w, red_b, pf);
    seq_kernel<<<BATCH * SEQLEN, 64, 0, stream>>>(ps, pf, sl, fl, xb);
    for (int l = 0; l < NLAYER; ++l) {
        qkv_kernel<<<BATCH * SEQLEN / 16, 192, 0, stream>>>(
            xb, qkv_w + (size_t)l * 3 * DMODEL * DMODEL, qkv_b + l * 3 * DMODEL, qkvb);
        attn_kernel<<<BATCH * NHEAD, 256, 0, stream>>>(qkvb, sl, fl, attno);
        projln_kernel<<<BATCH * SEQLEN, 64, 0, stream>>>(
            attno, out_w + (size_t)l * DMODEL * DMODEL, out_b + l * DMODEL,
            ln1_w + l * DMODEL, ln1_b + l * DMODEL, xb);
        ffnln_kernel<<<BATCH * SEQLEN, 128, 0, stream>>>(
            ff1_w + (size_t)l * FFDIM * DMODEL, ff1_b + l * FFDIM,
            ff2_w + (size_t)l * DMODEL * FFDIM, ff2_b + l * DMODEL,
            ln2_w + l * DMODEL, ln2_b + l * DMODEL, xb);
    }
    tpool_kernel<<<BATCH, 64, 0, stream>>>(xb, sl, fl, obuf);
}

extern "C" void kernel_launch(void* const* d_in, const int* in_sizes, int n_in,
                              void* d_out, int out_size, void* d_ws, size_t ws_size,
                              hipStream_t stream) {
    const float* pro1_x = (const float*)d_in[0];
    const int* ei1 = (const int*)d_in[1];
    const int* batch1 = (const int*)d_in[2];
    const float* pro2_x = (const float*)d_in[3];
    const int* ei2 = (const int*)d_in[4];
    const int* batch2 = (const int*)d_in[5];
    const float* mas1_s = (const float*)d_in[6];
    const int* mas1_sl = (const int*)d_in[7];
    const float* mas1_f = (const float*)d_in[8];
    const int* mas1_fl = (const int*)d_in[9];
    const float* mas2_s = (const float*)d_in[10];
    const int* mas2_sl = (const int*)d_in[11];
    const float* mas2_f = (const float*)d_in[12];
    const int* mas2_fl = (const int*)d_in[13];
    const float* gcn1_w = (const float*)d_in[14];
    const float* gcn1_b = (const float*)d_in[15];
    const float* fc1_w = (const float*)d_in[16];
    const float* fc1_b = (const float*)d_in[17];
    const float* gcn2_w = (const float*)d_in[18];
    const float* gcn2_b = (const float*)d_in[19];
    const float* fc2_w = (const float*)d_in[20];
    const float* fc2_b = (const float*)d_in[21];
    const float* red_w = (const float*)d_in[22];
    const float* red_b = (const float*)d_in[23];
    const float* t_qkv_w = (const float*)d_in[24];
    const float* t_qkv_b = (const float*)d_in[25];
    const float* t_out_w = (const float*)d_in[26];
    const float* t_out_b = (const float*)d_in[27];
    const float* t_ln1_w = (const float*)d_in[28];
    const float* t_ln1_b = (const float*)d_in[29];
    const float* t_ff1_w = (const float*)d_in[30];
    const float* t_ff1_b = (const float*)d_in[31];
    const float* t_ff2_w = (const float*)d_in[32];
    const float* t_ff2_b = (const float*)d_in[33];
    const float* t_ln2_w = (const float*)d_in[34];
    const float* t_ln2_b = (const float*)d_in[35];
    const float* fin_w = (const float*)d_in[36];
    const float* fin_b = (const float*)d_in[37];
    float* out = (float*)d_out;

    float* ws = (float*)d_ws;
    // region 1: h (N*FPD floats); after both GCN branches, reused for transformer buffers
    float* h = ws;
    // region 2: xhi+xlo (bf16, = N*FPD floats) during GEMM; then acc (gather output)
    float* region2 = h + (size_t)N_NODES * FPD;
    unsigned short* xhi = (unsigned short*)region2;
    unsigned short* xlo = xhi + (size_t)N_NODES * FPD;
    float* acc = region2;
    // tail: small persistent buffers
    float* tail = region2 + (size_t)N_NODES * FPD;
    unsigned short* whi = (unsigned short*)tail;
    unsigned short* wlo = whi + (size_t)FPD * FPD;
    float* fl = tail + (size_t)FPD * FPD;  // whi+wlo consumed FPD*FPD floats
    float* dinv = fl; fl += N_NODES;
    float* pooled = fl; fl += BATCH * FPD;
    float* feat1 = fl; fl += BATCH * ODIM;
    float* feat2 = fl; fl += BATCH * ODIM;
    int* cnt = (int*)fl; fl += N_NODES;
    int* rowptr = (int*)fl; fl += N_NODES + 64;
    int* cursor = (int*)fl; fl += N_NODES;
    int* adj = (int*)fl; fl += E_EDGES;
    int* bstart = (int*)fl; fl += 64;
    // transformer buffers alias region 1 (h dead after gather of branch 2)
    float* ps = h;
    float* pf = ps + (size_t)BATCH * LLEN * TDIM;
    float* xb = pf + (size_t)BATCH * LLEN * TDIM;
    float* qkvb = xb + (size_t)BATCH * SEQLEN * DMODEL;
    float* attno = qkvb + (size_t)BATCH * SEQLEN * 3 * DMODEL;
    float* o1 = attno + (size_t)BATCH * SEQLEN * DMODEL;
    float* o2 = o1 + BATCH * DMODEL;

    run_gcn_branch(pro1_x, ei1, batch1, gcn1_w, gcn1_b, fc1_w, fc1_b,
                   h, xhi, xlo, whi, wlo, acc, dinv, cnt, rowptr, cursor, adj,
                   bstart, pooled, feat1, stream);
    run_gcn_branch(pro2_x, ei2, batch2, gcn2_w, gcn2_b, fc2_w, fc2_b,
                   h, xhi, xlo, whi, wlo, acc, dinv, cnt, rowptr, cursor, adj,
                   bstart, pooled, feat2, stream);

    run_sequence(mas1_s, mas1_f, mas1_sl, mas1_fl, red_w, red_b,
                 t_qkv_w, t_qkv_b, t_out_w, t_out_b, t_ln1_w, t_ln1_b,
                 t_ff1_w, t_ff1_b, t_ff2_w, t_ff2_b, t_ln2_w, t_ln2_b,
                 ps, pf, xb, qkvb, attno, o1, stream);
    run_sequence(mas2_s, mas2_f, mas2_sl, mas2_fl, red_w, red_b,
                 t_qkv_w, t_qkv_b, t_out_w, t_out_b, t_ln1_w, t_ln1_b,
                 t_ff1_w, t_ff1_b, t_ff2_w, t_ff2_b, t_ln2_w, t_ln2_b,
                 ps, pf, xb, qkvb, attno, o2, stream);

    final_kernel<<<BATCH, 128, 0, stream>>>(feat1, feat2, o1, o2, fin_w, fin_b, out);
}